// Round 1
// baseline (8261.389 us; speedup 1.0000x reference)
//
#include <hip/hip_runtime.h>
#include <math.h>

#define BATCH 128
#define TT    12
#define CIN   10
#define HID   64
#define CTOT  74            // CIN + HID
#define OC    256           // 4*HID gate channels
#define KK    666           // CTOT*9
#define PLANE 625           // 25*25
#define HSZ   (BATCH*HID*PLANE)   // 5,120,000 floats per state buffer

__device__ __forceinline__ float fsigm(float v)  { return 1.f / (1.f + __expf(-v)); }
__device__ __forceinline__ float ftanh(float v)  { return 1.f - 2.f / (__expf(2.f*v) + 1.f); }

// -------- reorder conv_w (256,74,3,3) -> wre[(i*9+koff)*256 + j*4 + g] --------
__global__ void k_reorder(const float* __restrict__ w, float* __restrict__ wre) {
    int tid = blockIdx.x * 256 + threadIdx.x;
    if (tid >= OC * KK) return;
    int ik  = tid >> 8;          // (i*9 + koff) in [0,666)
    int rem = tid & 255;
    int j   = rem >> 2;
    int g   = rem & 3;
    wre[tid] = w[(g * HID + j) * KK + ik];
}

// -------- fused conv(3x3, 74ch -> 256ch) + LSTM pointwise, one timestep --------
__global__ __launch_bounds__(320) void k_step(
    const float* __restrict__ x, const float* __restrict__ wre,
    const float* __restrict__ bias, const float* __restrict__ hprev,
    float* __restrict__ hnext, float* __restrict__ cbuf, int t)
{
    __shared__ float  in_tile[CTOT * 189];   // [74][7 rows][27 cols], 55,944 B
    __shared__ float4 wls[1152];             // 2 in-ch * 9 * 64 lanes * 4 gates, 18,432 B

    const int tid  = threadIdx.x;
    const int rt   = blockIdx.x;             // row tile 0..4
    const int b    = blockIdx.y;             // batch
    const int r0   = rt * 5;
    const int wave = tid >> 6;               // 0..4 -> output row r0+wave
    const int j    = tid & 63;               // hid channel

    // ---- load input tile (x channels then h channels), zero-padded halo ----
    const float* xt = x + (size_t)(b * TT + t) * CIN * PLANE;
    const float* hp = hprev + (size_t)b * HID * PLANE;
    for (int idx = tid; idx < CTOT * 189; idx += 320) {
        int ch  = idx / 189;
        int rem = idx - ch * 189;
        int rr  = rem / 27;
        int cc  = rem - rr * 27;
        int gr  = r0 + rr - 1;
        int gc  = cc - 1;
        float v = 0.f;
        if ((unsigned)gr < 25u && (unsigned)gc < 25u) {
            v = (ch < CIN) ? xt[ch * PLANE + gr * 25 + gc]
                           : hp[(ch - CIN) * PLANE + gr * 25 + gc];
        }
        in_tile[idx] = v;
    }

    float acc0[25], acc1[25], acc2[25], acc3[25];
    #pragma unroll
    for (int p = 0; p < 25; ++p) { acc0[p] = 0.f; acc1[p] = 0.f; acc2[p] = 0.f; acc3[p] = 0.f; }

    const float4* wre4 = (const float4*)wre;
    for (int ic0 = 0; ic0 < CTOT; ic0 += 2) {
        __syncthreads();                       // protect wls reuse + first-iter tile load
        const float4* src = wre4 + ic0 * 576;  // 2*9*256/4 float4 per chunk
        for (int i2 = tid; i2 < 1152; i2 += 320) wls[i2] = src[i2];
        __syncthreads();

        for (int ii = 0; ii < 2; ++ii) {
            const float* itile = &in_tile[(ic0 + ii) * 189];
            for (int ky = 0; ky < 3; ++ky) {
                float row[27];
                const float* rsrc = itile + (wave + ky) * 27;
                #pragma unroll
                for (int cc = 0; cc < 27; ++cc) row[cc] = rsrc[cc];  // broadcast ds_read
                #pragma unroll
                for (int kx = 0; kx < 3; ++kx) {
                    float4 w4 = wls[(ii * 9 + ky * 3 + kx) * 64 + j]; // ds_read_b128
                    #pragma unroll
                    for (int p = 0; p < 25; ++p) {
                        acc0[p] = fmaf(row[p + kx], w4.x, acc0[p]);
                        acc1[p] = fmaf(row[p + kx], w4.y, acc1[p]);
                        acc2[p] = fmaf(row[p + kx], w4.z, acc2[p]);
                        acc3[p] = fmaf(row[p + kx], w4.w, acc3[p]);
                    }
                }
            }
        }
    }

    // ---- LSTM pointwise update for (b, j, row r0+wave, cols 0..24) ----
    const float bi = bias[j], bf = bias[HID + j], bo = bias[2 * HID + j], bg = bias[3 * HID + j];
    const int   r    = r0 + wave;
    const int   base = (b * HID + j) * PLANE + r * 25;
    float* cp = cbuf  + base;
    float* hn = hnext + base;
    #pragma unroll
    for (int p = 0; p < 25; ++p) {
        float iv = fsigm(acc0[p] + bi);
        float fv = fsigm(acc1[p] + bf);
        float ov = fsigm(acc2[p] + bo);
        float gv = ftanh(acc3[p] + bg);
        float cn = fv * cp[p] + iv * gv;
        cp[p] = cn;
        hn[p] = ov * ftanh(cn);
    }
}

// -------- MLP head: relu(h) -> 16 -> 8 -> 2 -> log_softmax --------
__global__ __launch_bounds__(256) void k_mlp(
    const float* __restrict__ hfin,
    const float* __restrict__ w1, const float* __restrict__ b1,
    const float* __restrict__ w2, const float* __restrict__ b2,
    const float* __restrict__ w3, const float* __restrict__ b3,
    float* __restrict__ out)
{
    __shared__ float red[256][17];
    __shared__ float hid1[16];
    __shared__ float hid2[8];
    const int b = blockIdx.x, tid = threadIdx.x;

    float acc[16];
    #pragma unroll
    for (int i = 0; i < 16; ++i) acc[i] = 0.f;

    const float* hb = hfin + (size_t)b * (HID * PLANE);
    for (int k = tid; k < HID * PLANE; k += 256) {
        float hv = hb[k];
        hv = hv > 0.f ? hv : 0.f;
        const float* wf = w1 + (size_t)k * 16;
        #pragma unroll
        for (int i = 0; i < 16; ++i) acc[i] = fmaf(hv, wf[i], acc[i]);
    }
    #pragma unroll
    for (int i = 0; i < 16; ++i) red[tid][i] = acc[i];
    __syncthreads();

    if (tid < 16) {
        float s = b1[tid];
        for (int t2 = 0; t2 < 256; ++t2) s += red[t2][tid];
        hid1[tid] = s > 0.f ? s : 0.f;
    }
    __syncthreads();
    if (tid < 8) {
        float s = b2[tid];
        #pragma unroll
        for (int k2 = 0; k2 < 16; ++k2) s += hid1[k2] * w2[k2 * 8 + tid];
        hid2[tid] = s > 0.f ? s : 0.f;
    }
    __syncthreads();
    if (tid == 0) {
        float l0 = b3[0], l1 = b3[1];
        #pragma unroll
        for (int k3 = 0; k3 < 8; ++k3) { l0 += hid2[k3] * w3[k3 * 2]; l1 += hid2[k3] * w3[k3 * 2 + 1]; }
        float m   = fmaxf(l0, l1);
        float lse = m + logf(__expf(l0 - m) + __expf(l1 - m));
        out[b * 2 + 0] = l0 - lse;
        out[b * 2 + 1] = l1 - lse;
    }
}

extern "C" void kernel_launch(void* const* d_in, const int* in_sizes, int n_in,
                              void* d_out, int out_size, void* d_ws, size_t ws_size,
                              hipStream_t stream) {
    const float* x      = (const float*)d_in[0];
    const float* conv_w = (const float*)d_in[1];
    const float* conv_b = (const float*)d_in[2];
    const float* w1     = (const float*)d_in[3];
    const float* b1     = (const float*)d_in[4];
    const float* w2     = (const float*)d_in[5];
    const float* b2     = (const float*)d_in[6];
    const float* w3     = (const float*)d_in[7];
    const float* b3     = (const float*)d_in[8];
    float* out = (float*)d_out;

    float* h0  = (float*)d_ws;          // ping-pong hidden state
    float* h1  = h0 + HSZ;
    float* c   = h1 + HSZ;              // cell state (in-place)
    float* wre = c + HSZ;               // reordered conv weights, 170,496 floats

    // ws is poisoned 0xAA and not re-poisoned between replays -> zero state every call
    hipMemsetAsync(h0, 0, (size_t)HSZ * sizeof(float), stream);
    hipMemsetAsync(c,  0, (size_t)HSZ * sizeof(float), stream);

    k_reorder<<<dim3((OC * KK) / 256), dim3(256), 0, stream>>>(conv_w, wre);

    for (int t = 0; t < TT; ++t) {
        float* hp = (t & 1) ? h1 : h0;
        float* hn = (t & 1) ? h0 : h1;
        k_step<<<dim3(5, BATCH), dim3(320), 0, stream>>>(x, wre, conv_b, hp, hn, c, t);
    }
    // after t=11, final h is in h0
    k_mlp<<<dim3(BATCH), dim3(256), 0, stream>>>(h0, w1, b1, w2, b2, w3, b3, out);
}